// Round 1
// baseline (700.851 us; speedup 1.0000x reference)
//
#include <hip/hip_runtime.h>
#include <hip/hip_bf16.h>

// Problem constants (fixed by the reference)
#define D_DIM   512
#define N_NODES 65536
#define M_MUT   32768

typedef __bf16 bf16x8 __attribute__((ext_vector_type(8)));
typedef float  f32x4  __attribute__((ext_vector_type(4)));

// round-to-nearest-even fp32 -> bf16 (inputs are finite; NaN not handled)
__device__ __forceinline__ unsigned short f2bf_rn(float f) {
    unsigned int u = __float_as_uint(f);
    u += 0x7FFFu + ((u >> 16) & 1u);
    return (unsigned short)(u >> 16);
}

// async global->LDS, 16 bytes per lane (LDS dest must be wave-uniform base; HW adds lane*16)
__device__ __forceinline__ void async_ld16(void* lds, const void* g) {
    __builtin_amdgcn_global_load_lds(
        (__attribute__((address_space(1))) void*)(void*)g,
        (__attribute__((address_space(3))) void*)lds,
        16, 0, 0);
}

// ---------------------------------------------------------------------------
// Cast/transpose the small parameter matrices to bf16 once per launch.
//   bto[n*512+k] = bf16(w_o[k*512+n])   (512x512)
//   btc[n*512+k] = bf16(w_c[k*512+n])   (512x512)
//   blw[i]       = bf16(lin_w[i])       (512x1024, already [n][k])
// ---------------------------------------------------------------------------
__global__ void cast_weights_kernel(const float* __restrict__ wo,
                                    const float* __restrict__ wc,
                                    const float* __restrict__ lw,
                                    unsigned short* __restrict__ bto,
                                    unsigned short* __restrict__ btc,
                                    unsigned short* __restrict__ blw)
{
    int t = blockIdx.x * 256 + threadIdx.x;   // 1,048,576 threads
    if (t < 262144) {
        int n = t >> 9, k = t & 511;
        bto[t] = f2bf_rn(wo[k * 512 + n]);
    } else if (t < 524288) {
        int u = t - 262144;
        int n = u >> 9, k = u & 511;
        btc[u] = f2bf_rn(wc[k * 512 + n]);
    } else {
        int u = t - 524288;
        blw[u] = f2bf_rn(lw[u]);
    }
}

// ---------------------------------------------------------------------------
// trans GEMM: out[m, n] = sum_k A[m,k] * W[k,n]
//   A rows 0..65535  = h_p (fp32), weight bto
//   A rows 65536..   = h_k (fp32), weight btc
// A is fp32 -> converted to bf16 in-register during LDS staging.
// 128x128 tile, BK=32, 256 threads (4 waves, 2x2 of 64x64 each).
// ---------------------------------------------------------------------------
__global__ __launch_bounds__(256)
void gemm_trans_kernel(const float* __restrict__ hp,
                       const float* __restrict__ hk,
                       const unsigned short* __restrict__ bto,
                       const unsigned short* __restrict__ btc,
                       float* __restrict__ out)
{
    // swizzled 1-D grid: bands of 16 m-tiles x 4 n-tiles (64 blocks) for L3 reuse of A
    const int bid  = blockIdx.x;           // 4096
    const int band = bid >> 6;
    const int rr_  = bid & 63;
    const int n0   = (rr_ & 3) * 128;
    const int m0   = (band * 16 + (rr_ >> 2)) * 128;

    const float* A;
    const unsigned short* Bt;
    if (m0 < N_NODES) { A = hp + (size_t)m0 * D_DIM;             Bt = bto; }
    else              { A = hk + (size_t)(m0 - N_NODES) * D_DIM; Bt = btc; }

    __shared__ __align__(16) unsigned short As[128 * 32];
    __shared__ __align__(16) unsigned short Bs[128 * 32];

    const int tid  = threadIdx.x;
    const int lane = tid & 63;
    const int wid  = tid >> 6;
    const int wm   = (wid & 1) * 64;
    const int wn   = (wid >> 1) * 64;
    const int r16  = lane & 15;
    const int q    = lane >> 4;

    f32x4 acc[4][4] = {};

    // A staging: 1024 float4-groups per K-step -> each thread: 2 groups of 8 floats
    const int ag_row = tid >> 2;           // 0..63  (+64 for i=1)
    const int ag_c8  = (tid & 3) * 8;      // 0,8,16,24

    for (int kk = 0; kk < 16; ++kk) {
        const int k0 = kk * 32;
        // ---- stage A: fp32 -> bf16 via VGPR round-trip ----
        #pragma unroll
        for (int i = 0; i < 2; ++i) {
            const int row = ag_row + i * 64;
            const float* src = A + (size_t)row * D_DIM + k0 + ag_c8;
            float4 v0 = *(const float4*)src;
            float4 v1 = *(const float4*)(src + 4);
            uint4 u;
            u.x = f2bf_rn(v0.x) | ((unsigned)f2bf_rn(v0.y) << 16);
            u.y = f2bf_rn(v0.z) | ((unsigned)f2bf_rn(v0.w) << 16);
            u.z = f2bf_rn(v1.x) | ((unsigned)f2bf_rn(v1.y) << 16);
            u.w = f2bf_rn(v1.z) | ((unsigned)f2bf_rn(v1.w) << 16);
            *(uint4*)&As[(row * 4 + (tid & 3)) * 8] = u;
        }
        // ---- stage B: async 16B/lane, LDS contiguous in lane order ----
        #pragma unroll
        for (int i = 0; i < 2; ++i) {
            const int c  = i * 256 + wid * 64 + lane;  // chunk 0..511
            const int bn = c >> 2, k8 = (c & 3) * 8;
            async_ld16(&Bs[(i * 256 + wid * 64) * 8],
                       Bt + (size_t)(n0 + bn) * D_DIM + k0 + k8);
        }
        __syncthreads();
        // ---- fragments + MFMA ----
        bf16x8 af[4], bfr[4];
        #pragma unroll
        for (int mi = 0; mi < 4; ++mi)
            af[mi] = *(const bf16x8*)&As[(wm + mi * 16 + r16) * 32 + q * 8];
        #pragma unroll
        for (int ni = 0; ni < 4; ++ni)
            bfr[ni] = *(const bf16x8*)&Bs[(wn + ni * 16 + r16) * 32 + q * 8];
        #pragma unroll
        for (int mi = 0; mi < 4; ++mi)
            #pragma unroll
            for (int ni = 0; ni < 4; ++ni)
                acc[mi][ni] = __builtin_amdgcn_mfma_f32_16x16x32_bf16(
                    af[mi], bfr[ni], acc[mi][ni], 0, 0, 0);
        __syncthreads();
    }

    // ---- epilogue: plain fp32 store (C/D layout: row = q*4+r, col = lane&15) ----
    #pragma unroll
    for (int mi = 0; mi < 4; ++mi) {
        #pragma unroll
        for (int ni = 0; ni < 4; ++ni) {
            const int mrow = m0 + wm + mi * 16 + q * 4;
            const int ncol = n0 + wn + ni * 16 + r16;
            float* p = out + (size_t)mrow * D_DIM + ncol;
            #pragma unroll
            for (int rr = 0; rr < 4; ++rr)
                p[(size_t)rr * D_DIM] = acc[mi][ni][rr];
        }
    }
}

// ---------------------------------------------------------------------------
// gather + tanh + bf16 cast:  g[m, 0:512]   = tanh(trans_hp[idxp[m], :])
//                             g[m, 512:1024]= tanh(trans_hk[idxk[m], :])
// ---------------------------------------------------------------------------
__global__ void gather_tanh_kernel(const float* __restrict__ trans,
                                   const int* __restrict__ idxp,
                                   const int* __restrict__ idxk,
                                   unsigned short* __restrict__ g)
{
    const int t  = blockIdx.x * 256 + threadIdx.x;  // M*256 threads
    const int m  = t >> 8;
    const int j4 = (t & 255) * 4;
    const float* src;
    if (j4 < 512) src = trans + (size_t)idxp[m] * 512 + j4;
    else          src = trans + (size_t)N_NODES * 512 + (size_t)idxk[m] * 512 + (j4 - 512);
    float4 v = *(const float4*)src;
    ushort4 o;
    o.x = f2bf_rn(tanhf(v.x));
    o.y = f2bf_rn(tanhf(v.y));
    o.z = f2bf_rn(tanhf(v.z));
    o.w = f2bf_rn(tanhf(v.w));
    *(ushort4*)&g[(size_t)m * 1024 + j4] = o;
}

// ---------------------------------------------------------------------------
// out GEMM + epilogue + scatter:
//   v = leaky_relu(g @ lin_w^T + lin_b, 0.01) + bias
//   out[idxp[m]*512 + n] = v ;  out[N*512*... second half ... idxk[m]*512 + n] = v
// A = g bf16 [32768,1024], Bt = blw bf16 [512,1024]; both staged async.
// ---------------------------------------------------------------------------
__global__ __launch_bounds__(256)
void gemm_out_kernel(const unsigned short* __restrict__ g,
                     const unsigned short* __restrict__ blw,
                     const float* __restrict__ lin_b,
                     const float* __restrict__ bias,
                     const int* __restrict__ idxp,
                     const int* __restrict__ idxk,
                     float* __restrict__ out)
{
    const int bid  = blockIdx.x;          // 1024
    const int band = bid >> 6;
    const int rr_  = bid & 63;
    const int n0   = (rr_ & 3) * 128;
    const int m0   = (band * 16 + (rr_ >> 2)) * 128;

    __shared__ __align__(16) unsigned short As[128 * 32];
    __shared__ __align__(16) unsigned short Bs[128 * 32];

    const int tid  = threadIdx.x;
    const int lane = tid & 63;
    const int wid  = tid >> 6;
    const int wm   = (wid & 1) * 64;
    const int wn   = (wid >> 1) * 64;
    const int r16  = lane & 15;
    const int q    = lane >> 4;

    f32x4 acc[4][4] = {};

    for (int kk = 0; kk < 32; ++kk) {     // K = 1024
        const int k0 = kk * 32;
        #pragma unroll
        for (int i = 0; i < 2; ++i) {
            const int c = i * 256 + wid * 64 + lane;
            const int ar = c >> 2, k8 = (c & 3) * 8;
            async_ld16(&As[(i * 256 + wid * 64) * 8],
                       g + (size_t)(m0 + ar) * 1024 + k0 + k8);
        }
        #pragma unroll
        for (int i = 0; i < 2; ++i) {
            const int c = i * 256 + wid * 64 + lane;
            const int bn = c >> 2, k8 = (c & 3) * 8;
            async_ld16(&Bs[(i * 256 + wid * 64) * 8],
                       blw + (size_t)(n0 + bn) * 1024 + k0 + k8);
        }
        __syncthreads();
        bf16x8 af[4], bfr[4];
        #pragma unroll
        for (int mi = 0; mi < 4; ++mi)
            af[mi] = *(const bf16x8*)&As[(wm + mi * 16 + r16) * 32 + q * 8];
        #pragma unroll
        for (int ni = 0; ni < 4; ++ni)
            bfr[ni] = *(const bf16x8*)&Bs[(wn + ni * 16 + r16) * 32 + q * 8];
        #pragma unroll
        for (int mi = 0; mi < 4; ++mi)
            #pragma unroll
            for (int ni = 0; ni < 4; ++ni)
                acc[mi][ni] = __builtin_amdgcn_mfma_f32_16x16x32_bf16(
                    af[mi], bfr[ni], acc[mi][ni], 0, 0, 0);
        __syncthreads();
    }

    // epilogue: +lin_b, leaky_relu(0.01), +bias, scatter to both halves of out
    int ip[4][4], ik[4][4];
    #pragma unroll
    for (int mi = 0; mi < 4; ++mi)
        #pragma unroll
        for (int rr = 0; rr < 4; ++rr) {
            const int m = m0 + wm + mi * 16 + q * 4 + rr;
            ip[mi][rr] = idxp[m];
            ik[mi][rr] = idxk[m];
        }
    const size_t half = (size_t)N_NODES * D_DIM;
    #pragma unroll
    for (int ni = 0; ni < 4; ++ni) {
        const int ncol = n0 + wn + ni * 16 + r16;
        const float lb = lin_b[ncol];
        const float bs = bias[ncol];
        #pragma unroll
        for (int mi = 0; mi < 4; ++mi)
            #pragma unroll
            for (int rr = 0; rr < 4; ++rr) {
                float v = acc[mi][ni][rr] + lb;
                v = v > 0.0f ? v : 0.01f * v;
                v += bs;
                out[(size_t)ip[mi][rr] * D_DIM + ncol] = v;
                out[half + (size_t)ik[mi][rr] * D_DIM + ncol] = v;
            }
    }
}

// ---------------------------------------------------------------------------
extern "C" void kernel_launch(void* const* d_in, const int* in_sizes, int n_in,
                              void* d_out, int out_size, void* d_ws, size_t ws_size,
                              hipStream_t stream)
{
    const float* h_p  = (const float*)d_in[0];
    const float* h_k  = (const float*)d_in[1];
    const int*   idxp = (const int*)d_in[2];
    const int*   idxk = (const int*)d_in[3];
    // d_in[4] = last_x (unused by the reference computation)
    const float* w_o  = (const float*)d_in[5];
    const float* w_c  = (const float*)d_in[6];
    const float* linw = (const float*)d_in[7];
    const float* linb = (const float*)d_in[8];
    const float* bias = (const float*)d_in[9];
    float* out = (float*)d_out;

    // workspace layout (bf16 as ushort): g[32768*1024] | bto[512*512] | btc[512*512] | blw[512*1024]
    unsigned short* g   = (unsigned short*)d_ws;
    unsigned short* bto = g + (size_t)M_MUT * 1024;
    unsigned short* btc = bto + 512 * 512;
    unsigned short* blw = btc + 512 * 512;
    // total ws: ~69 MB

    cast_weights_kernel<<<4096, 256, 0, stream>>>(w_o, w_c, linw, bto, btc, blw);
    gemm_trans_kernel<<<4096, 256, 0, stream>>>(h_p, h_k, bto, btc, out);
    gather_tanh_kernel<<<M_MUT, 256, 0, stream>>>(out, idxp, idxk, g);
    gemm_out_kernel<<<1024, 256, 0, stream>>>(g, blw, linb, bias, idxp, idxk, out);
}